// Round 11
// baseline (342.904 us; speedup 1.0000x reference)
//
#include <hip/hip_runtime.h>
#include <hip/hip_bf16.h>

// Problem constants
#define BB   4
#define HH   32
#define QQ   16
#define NN   4096
#define HKV  8
#define DD   128
#define NK   3072
#define GRP  4

typedef __attribute__((ext_vector_type(8))) short bf16x8;
typedef __attribute__((ext_vector_type(4))) float f32x4;

__device__ __forceinline__ unsigned int pack_bf16(float lo, float hi) {
    union { unsigned int u; __hip_bfloat16 h[2]; } p;
    p.h[0] = __float2bfloat16(lo);
    p.h[1] = __float2bfloat16(hi);
    return p.u;
}
__device__ __forceinline__ float bf_to_f(short bits) {
    union { unsigned int u; float f; } c;
    c.u = ((unsigned int)(unsigned short)bits) << 16;
    return c.f;
}

// ---------------------------------------------------------------------------
// Kernel 1 (round-5 body): gather + renormalize -> aw f32 (output 2) + bf16
// copy for k2. Block 0 additionally zeroes the 160 done-counters (32 ctx
// tiles + 128 out tiles) — required every call (no re-poison between replays).
// grid = 2048 blocks, 256 threads.
// ---------------------------------------------------------------------------
__global__ __launch_bounds__(256)
void k1_gather_norm(const float* __restrict__ attn_w,
                    const int* __restrict__ keep_idx,
                    float* __restrict__ aw_out,
                    __hip_bfloat16* __restrict__ aw16,
                    int* __restrict__ counters)
{
    if (blockIdx.x == 0 && threadIdx.x < 160) counters[threadIdx.x] = 0;

    const int row = blockIdx.x;                 // (b*H + h)*Q + q
    const float* src = attn_w + (size_t)row * NN;
    float* dst = aw_out + (size_t)row * NK;
    unsigned int* dst16 = reinterpret_cast<unsigned int*>(aw16 + (size_t)row * NK);

    __shared__ float vals[NK];
    __shared__ float red[256];

    float s = 0.f;
    for (int k = threadIdx.x; k < NK; k += 256) {
        float v = src[keep_idx[k]];
        vals[k] = v;
        s += v;
    }
    red[threadIdx.x] = s;
    __syncthreads();
    for (int st = 128; st > 0; st >>= 1) {
        if (threadIdx.x < st) red[threadIdx.x] += red[threadIdx.x + st];
        __syncthreads();
    }
    const float inv = 1.0f / (red[0] + 1e-6f);
    for (int k = threadIdx.x * 2; k < NK; k += 512) {
        float a = vals[k] * inv;
        float b = vals[k + 1] * inv;
        *reinterpret_cast<float2*>(&dst[k]) = make_float2(a, b);
        dst16[k >> 1] = pack_bf16(a, b);
    }
}

// ---------------------------------------------------------------------------
// Kernel 2 (round-5 body + last-block reduce tail).
// grid = B*HKV*SPLITK2 = 512 blocks, 512 threads (8 waves).
// Body identical to round 5 (bf16 MFMA, XOR-swizzled Vt, partial bf16).
// Tail: per tile t=(b*8+hkv), the 16th finishing block reduces the 16
// partials (L2-hot, fixed ss order -> deterministic) into ctxb [64][4096].
// ---------------------------------------------------------------------------
#define SPLITK2 16
#define KPB2    (NK / SPLITK2)   /* 192 */
#define KCH     64

__global__ __launch_bounds__(512, 4)
void k2_ctx(const __hip_bfloat16* __restrict__ aw16,
            const float* __restrict__ v_cache,
            const int* __restrict__ keep_idx,
            __hip_bfloat16* __restrict__ partial,
            __hip_bfloat16* __restrict__ ctxb,
            int* __restrict__ cnt_ctx)
{
    const int bid = blockIdx.x;          // ((b*8+hkv)*16 + ks)
    const int ks  = bid & 15;
    const int hkv = (bid >> 4) & 7;
    const int b   = bid >> 7;
    const int tid = threadIdx.x;
    const int lane = tid & 63;
    const int w    = tid >> 6;           // wave id 0..7
    const int mw   = w & 3;              // M-group: rows mw*16..+15
    const int nh   = w >> 2;             // d-half: tiles nh*4..nh*4+3
    const int fr   = lane & 15;          // fragment row/col
    const int kg   = lane >> 4;          // k-group (8 bf16)

    __shared__ unsigned short Vt[128 * 64];   // 16 KB, swizzled [d][k]
    __shared__ int idxs[KCH];
    __shared__ int lastFlag;

    const int k0 = ks * KPB2;
    const unsigned short* arow = reinterpret_cast<const unsigned short*>(aw16)
        + (size_t)((b * HH + hkv * GRP + mw) * QQ + fr) * NK + k0;
    const float* vb = v_cache + (size_t)(b * HKV + hkv) * NN * DD;

    f32x4 acc[4];
#pragma unroll
    for (int nt = 0; nt < 4; ++nt) acc[nt] = (f32x4){0.f, 0.f, 0.f, 0.f};

    const int sd  = tid & 127;
    const int sc0 = tid >> 7;            // 0..3

    for (int c = 0; c < KPB2; c += KCH) {
        __syncthreads();
        if (tid < KCH) idxs[tid] = keep_idx[k0 + c + tid];
        __syncthreads();

#pragma unroll
        for (int p = 0; p < 2; ++p) {
            const int cs = sc0 + 4 * p;
            float v[8];
#pragma unroll
            for (int e = 0; e < 8; ++e)
                v[e] = vb[(size_t)idxs[8 * cs + e] * DD + sd];
            uint4 pk;
            pk.x = pack_bf16(v[0], v[1]);
            pk.y = pack_bf16(v[2], v[3]);
            pk.z = pack_bf16(v[4], v[5]);
            pk.w = pack_bf16(v[6], v[7]);
            const int us = sd * 64 + ((cs ^ (sd & 7)) << 3);
            *reinterpret_cast<uint4*>(&Vt[us]) = pk;
        }
        __syncthreads();

#pragma unroll
        for (int kc = 0; kc < 2; ++kc) {
            bf16x8 af = *reinterpret_cast<const bf16x8*>(arow + c + kc * 32 + kg * 8);
            const int cs = kc * 4 + kg;
            const int xr = (cs ^ (fr & 7)) << 3;
#pragma unroll
            for (int nt = 0; nt < 4; ++nt) {
                const int d  = (nh * 4 + nt) * 16 + fr;
                const int us = d * 64 + xr;
                bf16x8 bf = *reinterpret_cast<const bf16x8*>(&Vt[us]);
                acc[nt] = __builtin_amdgcn_mfma_f32_16x16x32_bf16(af, bf, acc[nt], 0, 0, 0);
            }
        }
    }

    // write partial [bid][64][128] bf16 (round-5 layout: row = g*16+q)
    __hip_bfloat16* pb = partial + (size_t)bid * (64 * DD);
#pragma unroll
    for (int nt = 0; nt < 4; ++nt) {
#pragma unroll
        for (int reg = 0; reg < 4; ++reg) {
            const int row = mw * 16 + kg * 4 + reg;
            pb[row * DD + (nh * 4 + nt) * 16 + fr] = __float2bfloat16(acc[nt][reg]);
        }
    }

    // ----- last-block-done reduce tail -----
    __threadfence();                       // release partial stores
    const int tile = (b * 8 + hkv);
    if (tid == 0)
        lastFlag = (atomicAdd(&cnt_ctx[tile], 1) == SPLITK2 - 1);
    __syncthreads();
    if (!lastFlag) return;
    __threadfence();                       // acquire other blocks' partials

    const unsigned short* tp = reinterpret_cast<const unsigned short*>(
        partial + (size_t)tile * SPLITK2 * (64 * DD));
    // units: r(64) x ch(16 d-chunks of 8) = 1024 = 512 thr x 2
#pragma unroll
    for (int p = 0; p < 2; ++p) {
        const int u  = tid + 512 * p;
        const int r  = u >> 4;
        const int ch = u & 15;
        float sum[8];
#pragma unroll
        for (int e = 0; e < 8; ++e) sum[e] = 0.f;
#pragma unroll
        for (int ss = 0; ss < SPLITK2; ++ss) {
            bf16x8 v = *reinterpret_cast<const bf16x8*>(
                tp + (size_t)ss * (64 * DD) + r * DD + ch * 8);
#pragma unroll
            for (int e = 0; e < 8; ++e) sum[e] += bf_to_f(v[e]);
        }
        const int q = r & 15, g = r >> 4;
        const int bq = b * QQ + q;
        const int i  = (hkv * GRP + g) * DD + ch * 8;
        uint4 pk;
        pk.x = pack_bf16(sum[0], sum[1]);
        pk.y = pack_bf16(sum[2], sum[3]);
        pk.z = pack_bf16(sum[4], sum[5]);
        pk.w = pack_bf16(sum[6], sum[7]);
        *reinterpret_cast<uint4*>(reinterpret_cast<unsigned short*>(ctxb)
                                  + (size_t)bq * 4096 + i) = pk;
    }
}

// ---------------------------------------------------------------------------
// Kernel 4 (round-5 body + last-block reduce tail).
// grid = 128 N-tiles (32 o-cols) * 8 k-splits = 1024 blocks, 256 threads.
// Tail: per nt, the 8th finishing block reduces 8 pout slices -> out f32.
// ---------------------------------------------------------------------------
#define K4SPLIT 8
#define K4LEN   (4096 / K4SPLIT)  /* 512 */
#define KC4     128
#define LPAD    136               /* 128 + 8 ushort pad */

__global__ __launch_bounds__(256, 4)
void k4_gemm(const __hip_bfloat16* __restrict__ ctxb,
             const float* __restrict__ W,
             __hip_bfloat16* __restrict__ pout,
             float* __restrict__ out,
             int* __restrict__ cnt_out)
{
    const int nt  = blockIdx.x >> 3;   // 0..127
    const int ks  = blockIdx.x & 7;
    const int tid = threadIdx.x;
    const int lane = tid & 63;
    const int w    = tid >> 6;

    __shared__ unsigned short Al[64][LPAD];
    __shared__ unsigned short Bl[32][LPAD];
    __shared__ int lastFlag;

    f32x4 acc0 = {0.f, 0.f, 0.f, 0.f};
    f32x4 acc1 = {0.f, 0.f, 0.f, 0.f};

    const unsigned short* ctxu = reinterpret_cast<const unsigned short*>(ctxb);
    const int kbase = ks * K4LEN;
    const int fr = lane & 15;
    const int kg = lane >> 4;

    for (int ch = 0; ch < K4LEN / KC4; ++ch) {
        const int kb = kbase + ch * KC4;
        __syncthreads();

        {   // stage A: 64 rows x 128 bf16 (16B/thread x 4 passes)
            const int cc = tid & 15;
            const int r0 = tid >> 4;
#pragma unroll
            for (int p = 0; p < 4; ++p) {
                const int r = r0 + p * 16;
                float4 v = *reinterpret_cast<const float4*>(
                    ctxu + (size_t)r * 4096 + kb + cc * 8);
                *reinterpret_cast<float4*>(&Al[r][cc * 8]) = v;
            }
        }
        {   // stage B: 32 rows x 128 f32 -> bf16
            const int cc = tid & 31;
            const int r0 = tid >> 5;
#pragma unroll
            for (int p = 0; p < 4; ++p) {
                const int r = r0 + p * 8;
                float4 v = *reinterpret_cast<const float4*>(
                    W + (size_t)(nt * 32 + r) * 4096 + kb + cc * 4);
                union { ushort4 u4; __hip_bfloat16 h[4]; } pk;
                pk.h[0] = __float2bfloat16(v.x);
                pk.h[1] = __float2bfloat16(v.y);
                pk.h[2] = __float2bfloat16(v.z);
                pk.h[3] = __float2bfloat16(v.w);
                *reinterpret_cast<ushort4*>(&Bl[r][cc * 4]) = pk.u4;
            }
        }
        __syncthreads();

#pragma unroll
        for (int kst = 0; kst < KC4 / 32; ++kst) {
            const int ko = kst * 32 + kg * 8;
            bf16x8 a  = *reinterpret_cast<const bf16x8*>(&Al[w * 16 + fr][ko]);
            bf16x8 b0 = *reinterpret_cast<const bf16x8*>(&Bl[fr][ko]);
            bf16x8 b1 = *reinterpret_cast<const bf16x8*>(&Bl[16 + fr][ko]);
            acc0 = __builtin_amdgcn_mfma_f32_16x16x32_bf16(a, b0, acc0, 0, 0, 0);
            acc1 = __builtin_amdgcn_mfma_f32_16x16x32_bf16(a, b1, acc1, 0, 0, 0);
        }
    }

    // write pout [ks][64][4096] bf16 (round-5 layout)
    __hip_bfloat16* pb = pout + (size_t)ks * (64 * 4096);
#pragma unroll
    for (int reg = 0; reg < 4; ++reg) {
        const int row = w * 16 + kg * 4 + reg;
        pb[(size_t)row * 4096 + nt * 32 + fr]      = __float2bfloat16(acc0[reg]);
        pb[(size_t)row * 4096 + nt * 32 + 16 + fr] = __float2bfloat16(acc1[reg]);
    }

    // ----- last-block-done reduce tail (per nt) -----
    __threadfence();                       // release pout stores
    if (tid == 0)
        lastFlag = (atomicAdd(&cnt_out[nt], 1) == K4SPLIT - 1);
    __syncthreads();
    if (!lastFlag) return;
    __threadfence();                       // acquire

    const unsigned short* pp = reinterpret_cast<const unsigned short*>(pout);
    // units: r(64) x ch(4 chunks of 8 cols) = 256 = 256 thr x 1
    {
        const int r  = tid >> 2;
        const int ch = tid & 3;
        float sum[8];
#pragma unroll
        for (int e = 0; e < 8; ++e) sum[e] = 0.f;
#pragma unroll
        for (int ss = 0; ss < K4SPLIT; ++ss) {
            bf16x8 v = *reinterpret_cast<const bf16x8*>(
                pp + (size_t)ss * (64 * 4096) + (size_t)r * 4096 + nt * 32 + ch * 8);
#pragma unroll
            for (int e = 0; e < 8; ++e) sum[e] += bf_to_f(v[e]);
        }
        float* op = out + (size_t)r * 4096 + nt * 32 + ch * 8;
        *reinterpret_cast<float4*>(op)     = make_float4(sum[0], sum[1], sum[2], sum[3]);
        *reinterpret_cast<float4*>(op + 4) = make_float4(sum[4], sum[5], sum[6], sum[7]);
    }
}

// ---------------------------------------------------------------------------
extern "C" void kernel_launch(void* const* d_in, const int* in_sizes, int n_in,
                              void* d_out, int out_size, void* d_ws, size_t ws_size,
                              hipStream_t stream)
{
    const float* attn_w  = (const float*)d_in[0];   // [4][32][16][4096]
    const float* v_cache = (const float*)d_in[1];   // [4][8][4096][128]
    const float* o_proj  = (const float*)d_in[2];   // [4096][4096]
    const int*   keep_idx = (const int*)d_in[3];    // [3072]

    float* out    = (float*)d_out;                  // [4][16][4096] = 262144
    float* aw_out = (float*)d_out + 262144;         // [4][32][16][3072]

    // ws layout (bytes):
    //   [0, 8 MB)       : k2 bf16 partial [512][64][128] -- dead after k2 tail
    //   [0, 4 MB)       : k4 bf16 pout [8][64][4096]     -- reuses region
    //   [8 MB, 8.5 MB)  : ctxb bf16 [64][4096]
    //   [9 MB, 21 MB)   : aw16 bf16 copy
    //   [21 MB, +640B)  : counters: [0..31] ctx tiles, [32..159] out tiles
    __hip_bfloat16* partial2 = (__hip_bfloat16*)d_ws;
    __hip_bfloat16* ctxb = (__hip_bfloat16*)((char*)d_ws + (size_t)8 * 1024 * 1024);
    __hip_bfloat16* aw16 = (__hip_bfloat16*)((char*)d_ws + (size_t)9 * 1024 * 1024);
    int* counters = (int*)((char*)d_ws + (size_t)21 * 1024 * 1024);
    __hip_bfloat16* pout = (__hip_bfloat16*)d_ws;

    k1_gather_norm<<<BB * HH * QQ, 256, 0, stream>>>(attn_w, keep_idx, aw_out,
                                                     aw16, counters);
    k2_ctx<<<BB * HKV * SPLITK2, 512, 0, stream>>>(aw16, v_cache, keep_idx,
                                                   partial2, ctxb, counters);
    k4_gemm<<<128 * K4SPLIT, 256, 0, stream>>>(ctxb, o_proj, pout, out,
                                               counters + 32);
}

// Round 12
// 56.333 us; speedup vs baseline: 6.0871x; 6.0871x over previous
//
#include <hip/hip_runtime.h>
#include <hip/hip_bf16.h>

// Problem constants
#define BB   4
#define HH   32
#define QQ   16
#define NN   4096
#define HKV  8
#define DD   128
#define NK   3072
#define GRP  4

typedef __attribute__((ext_vector_type(8))) short bf16x8;
typedef __attribute__((ext_vector_type(4))) float f32x4;

__device__ __forceinline__ unsigned int pack_bf16(float lo, float hi) {
    union { unsigned int u; __hip_bfloat16 h[2]; } p;
    p.h[0] = __float2bfloat16(lo);
    p.h[1] = __float2bfloat16(hi);
    return p.u;
}

// ---------------------------------------------------------------------------
// Kernel 1: gather kept columns of attn_w, renormalize, write aw f32 (out 2).
// grid = B*H*Q = 2048 blocks, 256 threads. (No bf16 sidecar: k2 reads f32 aw
// L3-hot and packs in-register — round-4-proven.)
// ---------------------------------------------------------------------------
__global__ __launch_bounds__(256)
void k1_gather_norm(const float* __restrict__ attn_w,
                    const int* __restrict__ keep_idx,
                    float* __restrict__ aw_out)
{
    const int row = blockIdx.x;                 // (b*H + h)*Q + q
    const float* src = attn_w + (size_t)row * NN;
    float* dst = aw_out + (size_t)row * NK;

    __shared__ float vals[NK];
    __shared__ float red[256];

    float s = 0.f;
    for (int k = threadIdx.x; k < NK; k += 256) {
        float v = src[keep_idx[k]];
        vals[k] = v;
        s += v;
    }
    red[threadIdx.x] = s;
    __syncthreads();
    for (int st = 128; st > 0; st >>= 1) {
        if (threadIdx.x < st) red[threadIdx.x] += red[threadIdx.x + st];
        __syncthreads();
    }
    const float inv = 1.0f / (red[0] + 1e-6f);
    for (int k = threadIdx.x * 2; k < NK; k += 512) {
        float a = vals[k] * inv;
        float b = vals[k + 1] * inv;
        *reinterpret_cast<float2*>(&dst[k]) = make_float2(a, b);
    }
}

// ---------------------------------------------------------------------------
// Kernel 2 (round-4 body, verbatim): ctx partial GEMM via bf16 MFMA.
// grid = B*HKV*SPLITK2 = 512 blocks, 256 threads (4 waves).
// Wave w owns M-rows w*16..+15, all 8 N-tiles. A: f32 aw -> in-register bf16.
// B: gathered V transposed into LDS Vt[d][k] bf16, XOR chunk swizzle
//    us(d,cs) = d*64 + ((cs ^ (d&7))<<3); coverage (d,cs)=128*8=1024 units
//    = 4 passes x 256 threads. Partial: [bid][64][128] bf16.
// ---------------------------------------------------------------------------
#define SPLITK2 16
#define KPB2    (NK / SPLITK2)   /* 192 */
#define KCH     64

__global__ __launch_bounds__(256)
void k2_ctx(const float* __restrict__ aw,
            const float* __restrict__ v_cache,
            const int* __restrict__ keep_idx,
            __hip_bfloat16* __restrict__ partial)
{
    const int bid = blockIdx.x;          // ((b*8+hkv)*16 + ks)
    const int ks  = bid & 15;
    const int hkv = (bid >> 4) & 7;
    const int b   = bid >> 7;
    const int tid = threadIdx.x;
    const int lane = tid & 63;
    const int w    = tid >> 6;           // wave id -> M rows w*16..+15
    const int fr   = lane & 15;
    const int kg   = lane >> 4;

    __shared__ unsigned short Vt[128 * 64];   // 16 KB, swizzled [d][k]
    __shared__ int idxs[KCH];

    const int k0 = ks * KPB2;
    const float* arow = aw + (size_t)((b * HH + hkv * GRP + w) * QQ + fr) * NK + k0;
    const float* vb   = v_cache + (size_t)(b * HKV + hkv) * NN * DD;

    f32x4 acc[8];
#pragma unroll
    for (int nt = 0; nt < 8; ++nt) acc[nt] = (f32x4){0.f, 0.f, 0.f, 0.f};

    const int sd  = tid & 127;
    const int sc0 = tid >> 7;            // 0..1

    for (int c = 0; c < KPB2; c += KCH) {
        __syncthreads();
        if (tid < KCH) idxs[tid] = keep_idx[k0 + c + tid];
        __syncthreads();

#pragma unroll
        for (int p = 0; p < 4; ++p) {
            const int cs = sc0 + 2 * p;        // 16B chunk 0..7
            float v[8];
#pragma unroll
            for (int e = 0; e < 8; ++e)
                v[e] = vb[(size_t)idxs[8 * cs + e] * DD + sd];
            uint4 pk;
            pk.x = pack_bf16(v[0], v[1]);
            pk.y = pack_bf16(v[2], v[3]);
            pk.z = pack_bf16(v[4], v[5]);
            pk.w = pack_bf16(v[6], v[7]);
            const int us = sd * 64 + ((cs ^ (sd & 7)) << 3);
            *reinterpret_cast<uint4*>(&Vt[us]) = pk;
        }
        __syncthreads();

#pragma unroll
        for (int kc = 0; kc < 2; ++kc) {
            const float* ap = arow + c + kc * 32 + kg * 8;
            const float4 a0 = *reinterpret_cast<const float4*>(ap);
            const float4 a1 = *reinterpret_cast<const float4*>(ap + 4);
            union { bf16x8 v; unsigned int u[4]; } af;
            af.u[0] = pack_bf16(a0.x, a0.y);
            af.u[1] = pack_bf16(a0.z, a0.w);
            af.u[2] = pack_bf16(a1.x, a1.y);
            af.u[3] = pack_bf16(a1.z, a1.w);

            const int cs = kc * 4 + kg;
            const int xr = (cs ^ (fr & 7)) << 3;
#pragma unroll
            for (int nt = 0; nt < 8; ++nt) {
                const int d  = nt * 16 + fr;
                const int us = d * 64 + xr;
                bf16x8 bf = *reinterpret_cast<const bf16x8*>(&Vt[us]);
                acc[nt] = __builtin_amdgcn_mfma_f32_16x16x32_bf16(af.v, bf, acc[nt], 0, 0, 0);
            }
        }
    }

    __hip_bfloat16* pb = partial + (size_t)bid * (64 * DD);
#pragma unroll
    for (int nt = 0; nt < 8; ++nt) {
#pragma unroll
        for (int reg = 0; reg < 4; ++reg) {
            const int row = w * 16 + kg * 4 + reg;
            pb[row * DD + nt * 16 + fr] = __float2bfloat16(acc[nt][reg]);
        }
    }
}

// ---------------------------------------------------------------------------
// Kernel 3 (round-4/5 verbatim): reduce 16 bf16 partials -> ctxb [bq][i] bf16.
// ---------------------------------------------------------------------------
__global__ __launch_bounds__(256)
void k3_reduce(const __hip_bfloat16* __restrict__ partial,
               __hip_bfloat16* __restrict__ ctxb)
{
    const int flat = blockIdx.x * 256 + threadIdx.x;   // bq*4096 + i
    const int bq = flat >> 12;
    const int i  = flat & 4095;
    const int b = bq >> 4, q = bq & 15;
    const int h = i >> 7,  d = i & 127;
    const int hkv = h >> 2, g = h & 3;
    const int r = g * 16 + q;

    const __hip_bfloat16* p = partial
        + (size_t)((b * 8 + hkv) * SPLITK2) * (64 * DD) + r * DD + d;
    float s = 0.f;
#pragma unroll
    for (int ss = 0; ss < SPLITK2; ++ss)
        s += __bfloat162float(p[(size_t)ss * (64 * DD)]);
    ctxb[flat] = __float2bfloat16(s);
}

// ---------------------------------------------------------------------------
// Kernel 4' (round-8 body, verbatim): out = ctx @ W^T, in-block split-K,
// writes out f32 directly — no pout, no k5, no cross-block sync.
// grid = 256 N-tiles (16 o-cols each), 512 thr = 8 waves = 4 mw x 2 kh.
// Staging coverage: A units (ah,r,c8) = 2*64*16 = 2048 = 512 thr x 4 passes;
// B units (bh,r,cc) = 2*16*32 = 1024 = 512 thr x 2 passes.
// Epilogue: kh-pair reduce via LDS Rt, then plain f32 store.
// ---------------------------------------------------------------------------
#define KH4  2048
#define KC4  128
#define LPAD 136

__global__ __launch_bounds__(512, 2)
void k4_gemm(const __hip_bfloat16* __restrict__ ctxb,
             const float* __restrict__ W,
             float* __restrict__ out)
{
    const int nt  = blockIdx.x;        // o-cols nt*16 .. nt*16+15
    const int tid = threadIdx.x;
    const int lane = tid & 63;
    const int w    = tid >> 6;
    const int mw   = w & 3;            // M-rows mw*16..+15
    const int kh   = w >> 2;           // K-half
    const int fr   = lane & 15;
    const int kg   = lane >> 4;

    __shared__ unsigned short Al[2][64][LPAD];   // 34.8 KB
    __shared__ unsigned short Bl[2][16][LPAD];   //  8.7 KB
    __shared__ float Rt[4][16][16];              //  4.0 KB

    const unsigned short* ctxu = reinterpret_cast<const unsigned short*>(ctxb);
    f32x4 acc = {0.f, 0.f, 0.f, 0.f};

    for (int i = 0; i < 16; ++i) {
        __syncthreads();

        // stage A: 2048 bf16x8 units
#pragma unroll
        for (int p = 0; p < 4; ++p) {
            const int u  = tid + 512 * p;
            const int c8 = u & 15;
            const int r  = (u >> 4) & 63;
            const int ah = u >> 10;
            *reinterpret_cast<float4*>(&Al[ah][r][c8 * 8]) =
                *reinterpret_cast<const float4*>(
                    ctxu + (size_t)r * 4096 + ah * KH4 + i * KC4 + c8 * 8);
        }
        // stage B: 1024 float4 units, f32 -> bf16
#pragma unroll
        for (int p = 0; p < 2; ++p) {
            const int u  = tid + 512 * p;
            const int cc = u & 31;
            const int r  = (u >> 5) & 15;
            const int bh = u >> 9;
            float4 v = *reinterpret_cast<const float4*>(
                W + (size_t)(nt * 16 + r) * 4096 + bh * KH4 + i * KC4 + cc * 4);
            union { ushort4 u4; __hip_bfloat16 h[4]; } pk;
            pk.h[0] = __float2bfloat16(v.x);
            pk.h[1] = __float2bfloat16(v.y);
            pk.h[2] = __float2bfloat16(v.z);
            pk.h[3] = __float2bfloat16(v.w);
            *reinterpret_cast<ushort4*>(&Bl[bh][r][cc * 4]) = pk.u4;
        }
        __syncthreads();

#pragma unroll
        for (int kc = 0; kc < 4; ++kc) {
            const int ko = kc * 32 + kg * 8;
            bf16x8 a  = *reinterpret_cast<const bf16x8*>(&Al[kh][mw * 16 + fr][ko]);
            bf16x8 bv = *reinterpret_cast<const bf16x8*>(&Bl[kh][fr][ko]);
            acc = __builtin_amdgcn_mfma_f32_16x16x32_bf16(a, bv, acc, 0, 0, 0);
        }
    }

    // in-block K-half reduce, write out f32
    __syncthreads();
    if (kh == 1) {
#pragma unroll
        for (int reg = 0; reg < 4; ++reg)
            Rt[mw][kg * 4 + reg][fr] = acc[reg];
    }
    __syncthreads();
    if (kh == 0) {
#pragma unroll
        for (int reg = 0; reg < 4; ++reg) {
            const int bq = mw * 16 + kg * 4 + reg;
            out[(size_t)bq * 4096 + nt * 16 + fr] = acc[reg] + Rt[mw][kg * 4 + reg][fr];
        }
    }
}

// ---------------------------------------------------------------------------
extern "C" void kernel_launch(void* const* d_in, const int* in_sizes, int n_in,
                              void* d_out, int out_size, void* d_ws, size_t ws_size,
                              hipStream_t stream)
{
    const float* attn_w  = (const float*)d_in[0];   // [4][32][16][4096]
    const float* v_cache = (const float*)d_in[1];   // [4][8][4096][128]
    const float* o_proj  = (const float*)d_in[2];   // [4096][4096]
    const int*   keep_idx = (const int*)d_in[3];    // [3072]

    float* out    = (float*)d_out;                  // [4][16][4096] = 262144
    float* aw_out = (float*)d_out + 262144;         // [4][32][16][3072]

    // ws layout (bytes):
    //   [0, 8 MB)       : k2 bf16 partial [512][64][128] -- dead after k3
    //   [8 MB, 8.5 MB)  : ctxb bf16 [64][4096]
    __hip_bfloat16* partial2 = (__hip_bfloat16*)d_ws;
    __hip_bfloat16* ctxb = (__hip_bfloat16*)((char*)d_ws + (size_t)8 * 1024 * 1024);

    k1_gather_norm<<<BB * HH * QQ, 256, 0, stream>>>(attn_w, keep_idx, aw_out);
    k2_ctx<<<BB * HKV * SPLITK2, 256, 0, stream>>>(aw_out, v_cache, keep_idx, partial2);
    k3_reduce<<<(64 * 4096) / 256, 256, 0, stream>>>(partial2, ctxb);
    k4_gemm<<<256, 512, 0, stream>>>(ctxb, o_proj, out);
}

// Round 15
// 48.399 us; speedup vs baseline: 7.0850x; 1.1639x over previous
//
#include <hip/hip_runtime.h>
#include <hip/hip_bf16.h>

// Problem constants
#define BB   4
#define HH   32
#define QQ   16
#define NN   4096
#define HKV  8
#define DD   128
#define NK   3072
#define GRP  4

typedef __attribute__((ext_vector_type(8))) short bf16x8;
typedef __attribute__((ext_vector_type(4))) float f32x4;

__device__ __forceinline__ unsigned int pack_bf16(float lo, float hi) {
    union { unsigned int u; __hip_bfloat16 h[2]; } p;
    p.h[0] = __float2bfloat16(lo);
    p.h[1] = __float2bfloat16(hi);
    return p.u;
}

// ---------------------------------------------------------------------------
// Kernel 1: gather + renormalize -> aw f32 (output 2) + bf16 copy for k2.
// grid = B*H*Q = 2048 blocks, 256 threads.  [round-5 verbatim, 48.5 µs config]
// ---------------------------------------------------------------------------
__global__ __launch_bounds__(256)
void k1_gather_norm(const float* __restrict__ attn_w,
                    const int* __restrict__ keep_idx,
                    float* __restrict__ aw_out,
                    __hip_bfloat16* __restrict__ aw16)
{
    const int row = blockIdx.x;                 // (b*H + h)*Q + q
    const float* src = attn_w + (size_t)row * NN;
    float* dst = aw_out + (size_t)row * NK;
    unsigned int* dst16 = reinterpret_cast<unsigned int*>(aw16 + (size_t)row * NK);

    __shared__ float vals[NK];
    __shared__ float red[256];

    float s = 0.f;
    for (int k = threadIdx.x; k < NK; k += 256) {
        float v = src[keep_idx[k]];
        vals[k] = v;
        s += v;
    }
    red[threadIdx.x] = s;
    __syncthreads();
    for (int st = 128; st > 0; st >>= 1) {
        if (threadIdx.x < st) red[threadIdx.x] += red[threadIdx.x + st];
        __syncthreads();
    }
    const float inv = 1.0f / (red[0] + 1e-6f);
    for (int k = threadIdx.x * 2; k < NK; k += 512) {
        float a = vals[k] * inv;
        float b = vals[k + 1] * inv;
        *reinterpret_cast<float2*>(&dst[k]) = make_float2(a, b);
        dst16[k >> 1] = pack_bf16(a, b);
    }
}

// ---------------------------------------------------------------------------
// Kernel 2: ctx partial GEMM via bf16 MFMA.  [round-5 verbatim]
// grid = B*HKV*SPLITK2 = 512 blocks, 512 threads (8 waves).
// Wave w: mw = w&3 (M rows mw*16..+15), nh = w>>2 (d-half).
//   B: gathered V staged transposed into LDS Vt[d][k] bf16, XOR chunk swizzle
//      us(d,cs) = d*64 + ((cs ^ (d&7))<<3), cs = 16B chunk (8 k) 0..7.
//      Coverage: unit=(d,cs) -> 128*8 = 1024 units = 2 passes x 512 threads.
// Partial: [bid][64][128] bf16.
// ---------------------------------------------------------------------------
#define SPLITK2 16
#define KPB2    (NK / SPLITK2)   /* 192 */
#define KCH     64

__global__ __launch_bounds__(512, 4)
void k2_ctx(const __hip_bfloat16* __restrict__ aw16,
            const float* __restrict__ v_cache,
            const int* __restrict__ keep_idx,
            __hip_bfloat16* __restrict__ partial)
{
    const int bid = blockIdx.x;          // ((b*8+hkv)*16 + ks)
    const int ks  = bid & 15;
    const int hkv = (bid >> 4) & 7;
    const int b   = bid >> 7;
    const int tid = threadIdx.x;
    const int lane = tid & 63;
    const int w    = tid >> 6;           // wave id 0..7
    const int mw   = w & 3;              // M-group: rows mw*16..+15
    const int nh   = w >> 2;             // d-half: tiles nh*4..nh*4+3
    const int fr   = lane & 15;          // fragment row/col
    const int kg   = lane >> 4;          // k-group (8 bf16)

    __shared__ unsigned short Vt[128 * 64];   // 16 KB, swizzled [d][k]
    __shared__ int idxs[KCH];

    const int k0 = ks * KPB2;
    const unsigned short* arow = reinterpret_cast<const unsigned short*>(aw16)
        + (size_t)((b * HH + hkv * GRP + mw) * QQ + fr) * NK + k0;
    const float* vb = v_cache + (size_t)(b * HKV + hkv) * NN * DD;

    f32x4 acc[4];
#pragma unroll
    for (int nt = 0; nt < 4; ++nt) acc[nt] = (f32x4){0.f, 0.f, 0.f, 0.f};

    // staging: pass p, thread t -> unit u = t + 512p; d = u&127, cs = u>>7
    const int sd  = tid & 127;
    const int sc0 = tid >> 7;            // 0..3

    for (int c = 0; c < KPB2; c += KCH) {
        __syncthreads();                       // Vt free (prev compute done)
        if (tid < KCH) idxs[tid] = keep_idx[k0 + c + tid];
        __syncthreads();                       // idxs ready

#pragma unroll
        for (int p = 0; p < 2; ++p) {
            const int cs = sc0 + 4 * p;        // 16B chunk 0..7 (k = 8cs..8cs+7)
            float v[8];
#pragma unroll
            for (int e = 0; e < 8; ++e)
                v[e] = vb[(size_t)idxs[8 * cs + e] * DD + sd];
            uint4 pk;
            pk.x = pack_bf16(v[0], v[1]);
            pk.y = pack_bf16(v[2], v[3]);
            pk.z = pack_bf16(v[4], v[5]);
            pk.w = pack_bf16(v[6], v[7]);
            const int us = sd * 64 + ((cs ^ (sd & 7)) << 3);
            *reinterpret_cast<uint4*>(&Vt[us]) = pk;
        }
        __syncthreads();                       // Vt ready

#pragma unroll
        for (int kc = 0; kc < 2; ++kc) {
            bf16x8 af = *reinterpret_cast<const bf16x8*>(arow + c + kc * 32 + kg * 8);
            const int cs = kc * 4 + kg;        // 16B chunk index along k
            const int xr = (cs ^ (fr & 7)) << 3;
#pragma unroll
            for (int nt = 0; nt < 4; ++nt) {
                const int d  = (nh * 4 + nt) * 16 + fr;
                const int us = d * 64 + xr;    // (d&7) == (fr&7)
                bf16x8 bf = *reinterpret_cast<const bf16x8*>(&Vt[us]);
                acc[nt] = __builtin_amdgcn_mfma_f32_16x16x32_bf16(af, bf, acc[nt], 0, 0, 0);
            }
        }
    }

    // epilogue: C/D layout col=lane&15 (d within tile), row=(lane>>4)*4+reg
    __hip_bfloat16* pb = partial + (size_t)bid * (64 * DD);
#pragma unroll
    for (int nt = 0; nt < 4; ++nt) {
#pragma unroll
        for (int reg = 0; reg < 4; ++reg) {
            const int row = mw * 16 + kg * 4 + reg;
            pb[row * DD + (nh * 4 + nt) * 16 + fr] = __float2bfloat16(acc[nt][reg]);
        }
    }
}

// ---------------------------------------------------------------------------
// Kernel 3: reduce the 16 bf16 k-split partials -> ctxb [bq][i] bf16.
// [round-5 verbatim]
// ---------------------------------------------------------------------------
__global__ __launch_bounds__(256)
void k3_reduce(const __hip_bfloat16* __restrict__ partial,
               __hip_bfloat16* __restrict__ ctxb)
{
    const int flat = blockIdx.x * 256 + threadIdx.x;   // bq*4096 + i
    const int bq = flat >> 12;
    const int i  = flat & 4095;
    const int b = bq >> 4, q = bq & 15;
    const int h = i >> 7,  d = i & 127;
    const int hkv = h >> 2, g = h & 3;
    const int r = g * 16 + q;

    const __hip_bfloat16* p = partial
        + (size_t)((b * 8 + hkv) * SPLITK2) * (64 * DD) + r * DD + d;
    float s = 0.f;
#pragma unroll
    for (int ss = 0; ss < SPLITK2; ++ss)
        s += __bfloat162float(p[(size_t)ss * (64 * DD)]);
    ctxb[flat] = __float2bfloat16(s);
}

// ---------------------------------------------------------------------------
// Kernel 4: out = ctx @ W^T via bf16 MFMA, M=64 x N=4096 x K=4096.
// grid = 128 N-tiles (32 o-cols) * 8 k-splits = 1024 blocks, 256 threads.
// [round-5 verbatim: cross-block k-split reduced by k5 — correct by design]
// ---------------------------------------------------------------------------
#define K4SPLIT 8
#define K4LEN   (4096 / K4SPLIT)  /* 512 */
#define KC4     128
#define LPAD    136               /* 128 + 8 ushort pad */

__global__ __launch_bounds__(256, 4)
void k4_gemm(const __hip_bfloat16* __restrict__ ctxb,
             const float* __restrict__ W,
             __hip_bfloat16* __restrict__ pout)
{
    const int nt  = blockIdx.x >> 3;   // 0..127  (o-cols nt*32 .. nt*32+31)
    const int ks  = blockIdx.x & 7;
    const int tid = threadIdx.x;
    const int lane = tid & 63;
    const int w    = tid >> 6;         // wave id: M-rows w*16 .. w*16+15

    __shared__ unsigned short Al[64][LPAD];   // ctx bf16 tile
    __shared__ unsigned short Bl[32][LPAD];   // W   bf16 tile

    f32x4 acc0 = {0.f, 0.f, 0.f, 0.f};
    f32x4 acc1 = {0.f, 0.f, 0.f, 0.f};

    const unsigned short* ctxu = reinterpret_cast<const unsigned short*>(ctxb);
    const int kbase = ks * K4LEN;
    const int fr = lane & 15;          // fragment row/col
    const int kg = lane >> 4;          // k-group (8 bf16 each)

    for (int ch = 0; ch < K4LEN / KC4; ++ch) {
        const int kb = kbase + ch * KC4;
        __syncthreads();

        // stage A: 64 rows x 128 bf16 (16B/thread x 4 passes)
        {
            const int cc = tid & 15;       // 8-ushort chunk within row
            const int r0 = tid >> 4;       // 16 rows per pass
#pragma unroll
            for (int p = 0; p < 4; ++p) {
                const int r = r0 + p * 16;
                float4 v = *reinterpret_cast<const float4*>(
                    ctxu + (size_t)r * 4096 + kb + cc * 8);
                *reinterpret_cast<float4*>(&Al[r][cc * 8]) = v;
            }
        }
        // stage B: 32 rows x 128 f32 -> bf16 (float4/thread x 4 passes)
        {
            const int cc = tid & 31;       // float4 col
            const int r0 = tid >> 5;       // 8 rows per pass
#pragma unroll
            for (int p = 0; p < 4; ++p) {
                const int r = r0 + p * 8;
                float4 v = *reinterpret_cast<const float4*>(
                    W + (size_t)(nt * 32 + r) * 4096 + kb + cc * 4);
                union { ushort4 u; __hip_bfloat16 h[4]; } pk;
                pk.h[0] = __float2bfloat16(v.x);
                pk.h[1] = __float2bfloat16(v.y);
                pk.h[2] = __float2bfloat16(v.z);
                pk.h[3] = __float2bfloat16(v.w);
                *reinterpret_cast<ushort4*>(&Bl[r][cc * 4]) = pk.u;
            }
        }
        __syncthreads();

#pragma unroll
        for (int kst = 0; kst < KC4 / 32; ++kst) {
            const int ko = kst * 32 + kg * 8;
            bf16x8 a  = *reinterpret_cast<const bf16x8*>(&Al[w * 16 + fr][ko]);
            bf16x8 b0 = *reinterpret_cast<const bf16x8*>(&Bl[fr][ko]);
            bf16x8 b1 = *reinterpret_cast<const bf16x8*>(&Bl[16 + fr][ko]);
            acc0 = __builtin_amdgcn_mfma_f32_16x16x32_bf16(a, b0, acc0, 0, 0, 0);
            acc1 = __builtin_amdgcn_mfma_f32_16x16x32_bf16(a, b1, acc1, 0, 0, 0);
        }
    }

    // epilogue: C/D layout col=lane&15, row=(lane>>4)*4+reg
    __hip_bfloat16* pb = pout + (size_t)ks * (64 * 4096);
#pragma unroll
    for (int reg = 0; reg < 4; ++reg) {
        const int row = w * 16 + kg * 4 + reg;
        pb[(size_t)row * 4096 + nt * 32 + fr]      = __float2bfloat16(acc0[reg]);
        pb[(size_t)row * 4096 + nt * 32 + 16 + fr] = __float2bfloat16(acc1[reg]);
    }
}

// ---------------------------------------------------------------------------
// Kernel 5: reduce the 8 bf16 k-split output partials -> out (output 1).
// [round-5 verbatim]
// ---------------------------------------------------------------------------
__global__ __launch_bounds__(256)
void k5_out(const __hip_bfloat16* __restrict__ pout, float* __restrict__ out)
{
    const int flat = blockIdx.x * 256 + threadIdx.x;
    float s = 0.f;
#pragma unroll
    for (int ss = 0; ss < K4SPLIT; ++ss)
        s += __bfloat162float(pout[(size_t)ss * (64 * 4096) + flat]);
    out[flat] = s;
}

// ---------------------------------------------------------------------------
extern "C" void kernel_launch(void* const* d_in, const int* in_sizes, int n_in,
                              void* d_out, int out_size, void* d_ws, size_t ws_size,
                              hipStream_t stream)
{
    const float* attn_w  = (const float*)d_in[0];   // [4][32][16][4096]
    const float* v_cache = (const float*)d_in[1];   // [4][8][4096][128]
    const float* o_proj  = (const float*)d_in[2];   // [4096][4096]
    const int*   keep_idx = (const int*)d_in[3];    // [3072]

    float* out    = (float*)d_out;                  // [4][16][4096] = 262144
    float* aw_out = (float*)d_out + 262144;         // [4][32][16][3072]

    // ws layout (bytes):
    //   [0, 8 MB)       : k2 bf16 partial (4,194,304 bf16) -- dead after k3
    //   [0, 4 MB)       : k4 bf16 pout (2,097,152 bf16)    -- reuses region
    //   [8 MB, 8.5 MB)  : ctx bf16 (262,144 bf16)
    //   [9 MB, 21 MB)   : aw bf16 copy (6,291,456 bf16)
    __hip_bfloat16* partial2 = (__hip_bfloat16*)d_ws;
    __hip_bfloat16* ctxb = (__hip_bfloat16*)((char*)d_ws + (size_t)8 * 1024 * 1024);
    __hip_bfloat16* aw16 = (__hip_bfloat16*)((char*)d_ws + (size_t)9 * 1024 * 1024);
    __hip_bfloat16* pout = (__hip_bfloat16*)d_ws;

    k1_gather_norm<<<BB * HH * QQ, 256, 0, stream>>>(attn_w, keep_idx, aw_out, aw16);
    k2_ctx<<<BB * HKV * SPLITK2, 512, 0, stream>>>(aw16, v_cache, keep_idx, partial2);
    k3_reduce<<<(64 * 4096) / 256, 256, 0, stream>>>(partial2, ctxb);
    k4_gemm<<<128 * K4SPLIT, 256, 0, stream>>>(ctxb, o_proj, pout);
    k5_out<<<(64 * 4096) / 256, 256, 0, stream>>>(pout, out);
}